// Round 15
// baseline (313.854 us; speedup 1.0000x reference)
//
#include <hip/hip_runtime.h>
#include <hip/hip_bf16.h>
#include <math.h>

// Problem constants
#define BATCH 4
#define SEQ   2048
#define HID   768
#define INTER 1536
#define DK    128
#define NTOT  3200      // 2*INTER + DK
#define MROWS 8192      // BATCH*SEQ
#define LN512 6.2383246250395075f

typedef _Float16 half8   __attribute__((ext_vector_type(8)));
typedef float    floatx4 __attribute__((ext_vector_type(4)));
typedef float    floatx16 __attribute__((ext_vector_type(16)));

typedef const __attribute__((address_space(1))) unsigned int* gas1_t;
typedef __attribute__((address_space(3))) unsigned int* las3_t;

static __device__ __forceinline__ void load16(const _Float16* g, _Float16* l) {
    __builtin_amdgcn_global_load_lds((gas1_t)g, (las3_t)l, 16, 0, 0);
}
#define WAIT_VM(N)    asm volatile("s_waitcnt vmcnt(" #N ")" ::: "memory")
#define WAIT_LGKM0()  asm volatile("s_waitcnt lgkmcnt(0)" ::: "memory")
#define BARRIER_RAW() asm volatile("s_barrier" ::: "memory")

// ---------------------------------------------------------------- prep kernels
__global__ void cast_h_kernel(const float* __restrict__ in, _Float16* __restrict__ out, int n) {
    int i = (blockIdx.x * blockDim.x + threadIdx.x) * 8;
    if (i < n) {
        float4 a = *reinterpret_cast<const float4*>(in + i);
        float4 b = *reinterpret_cast<const float4*>(in + i + 4);
        half8 h = {(_Float16)a.x, (_Float16)a.y, (_Float16)a.z, (_Float16)a.w,
                   (_Float16)b.x, (_Float16)b.y, (_Float16)b.z, (_Float16)b.w};
        *reinterpret_cast<half8*>(out + i) = h;
    }
}

__global__ void trans_wi_kernel(const float* __restrict__ Wi, _Float16* __restrict__ WiT) {
    __shared__ _Float16 tile[32][33];
    const int c0 = blockIdx.x * 32, r0 = blockIdx.y * 32;
    const int tx = threadIdx.x, ty = threadIdx.y;
#pragma unroll
    for (int j = 0; j < 32; j += 8)
        tile[tx][ty + j] = (_Float16)Wi[(size_t)(r0 + ty + j) * NTOT + c0 + tx];
    __syncthreads();
#pragma unroll
    for (int j = 0; j < 32; j += 8)
        WiT[(size_t)(c0 + ty + j) * HID + r0 + tx] = tile[ty + j][tx];
}

__global__ void trans_wo_kernel(const float* __restrict__ Wo, _Float16* __restrict__ WoT) {
    __shared__ _Float16 tile[32][33];
    const int c0 = blockIdx.x * 32, r0 = blockIdx.y * 32;
    const int tx = threadIdx.x, ty = threadIdx.y;
#pragma unroll
    for (int j = 0; j < 32; j += 8)
        tile[tx][ty + j] = (_Float16)Wo[(size_t)(r0 + ty + j) * HID + c0 + tx];
    __syncthreads();
#pragma unroll
    for (int j = 0; j < 32; j += 8)
        WoT[(size_t)(c0 + ty + j) * INTER + r0 + tx] = tile[ty + j][tx];
}

__global__ void mask_scales_kernel(const int* __restrict__ mask, float* __restrict__ scales) {
    __shared__ int sh[256];
    int b = blockIdx.x;
    int s = 0;
    for (int i = threadIdx.x; i < SEQ; i += 256) s += mask[b * SEQ + i];
    sh[threadIdx.x] = s;
    __syncthreads();
    for (int off = 128; off > 0; off >>= 1) {
        if (threadIdx.x < off) sh[threadIdx.x] += sh[threadIdx.x + off];
        __syncthreads();
    }
    if (threadIdx.x == 0) scales[b] = logf((float)sh[0]) / LN512;
}

// ---------------------------------------------------------------- shared tile ctx
struct TileCtx {
    int tid, wave, lane, quad, l16, l31, half, wm, wn, c0, c1;
};
static __device__ __forceinline__ TileCtx make_ctx() {
    TileCtx t;
    t.tid = threadIdx.x;
    t.wave = t.tid >> 6; t.lane = t.tid & 63;
    t.quad = t.lane >> 4; t.l16 = t.lane & 15;
    t.l31 = t.lane & 31;  t.half = t.lane >> 5;
    t.wm = (t.wave & 1) * 64;
    t.wn = (t.wave >> 1) * 64;
    t.c0 = t.tid;
    t.c1 = t.tid + 256;
    return t;
}

// ================================================================ mainloop: 32x32x16, 3-slot/48KB, 1 barrier/iter
// C(128x128) += A(128xK) * BT(128xK)^T. 4 waves 2x2; wave does 64x64 = 2x2 MFMA 32x32.
// LDS swizzle s32(r) = ((r>>1)^(r>>3))&3 applied to 16B k-chunks within each 64B row:
// all 32 fragment-read lanes hit distinct bank groups. DMA side fetches the matching
// permuted global chunk (same 64B row -> coalescing unchanged).
// Per iter k: vm-wait(4) [tile k landed, k+1 in flight] -> barrier -> DMA k+2 into
// slot (k+2)%3 [slot consumed at k-1, readers lgkm-pinned] -> ds_read + 8 MFMA -> lgkm-pin.
static __device__ __forceinline__ void gemm_mainloop_3s32(
    const TileCtx& t,
    const _Float16* __restrict__ Ag, int lda,
    const _Float16* __restrict__ Bg, int ldb,
    int K, _Float16* smem, floatx16 acc[2][2])
{
    const int r0i = t.c0 >> 2, s0 = (((r0i >> 1) ^ (r0i >> 3)) & 3);
    const int r1i = t.c1 >> 2, s1 = (((r1i >> 1) ^ (r1i >> 3)) & 3);
    const int ak0 = ((t.c0 & 3) ^ s0) * 8;
    const int ak1 = ((t.c1 & 3) ^ s1) * 8;
    const _Float16* a0 = Ag + (size_t)r0i * lda + ak0;
    const _Float16* a1 = Ag + (size_t)r1i * lda + ak1;
    const _Float16* b0 = Bg + (size_t)r0i * ldb + ak0;
    const _Float16* b1 = Bg + (size_t)r1i * ldb + ak1;
    _Float16* Asl = smem + t.c0 * 8;
    _Float16* Bsl = smem + 12288 + t.c0 * 8;
    const int nIter = K >> 5;

    const int fsw = ((t.l31 >> 1) ^ (t.l31 >> 3)) & 3;

    load16(a0, Asl);        load16(a1, Asl + 2048);
    load16(b0, Bsl);        load16(b1, Bsl + 2048);
    if (nIter > 1) {
        load16(a0 + 32, Asl + 4096); load16(a1 + 32, Asl + 6144);
        load16(b0 + 32, Bsl + 4096); load16(b1 + 32, Bsl + 6144);
    }

    int sc = 0, sp = 2;
    for (int k = 0; k < nIter; ++k) {
        if (k + 1 < nIter) { WAIT_VM(4); } else { WAIT_VM(0); }
        BARRIER_RAW();
        if (k + 2 < nIter) {
            const int off = sp * 4096;
            const int k0 = (k + 2) << 5;
            load16(a0 + k0, Asl + off); load16(a1 + k0, Asl + off + 2048);
            load16(b0 + k0, Bsl + off); load16(b1 + k0, Bsl + off + 2048);
        }
        const _Float16* Ab = smem + sc * 4096;
        const _Float16* Bb = smem + 12288 + sc * 4096;
        half8 af[2][2], bf[2][2];   // [tile][kstep]
#pragma unroll
        for (int mt = 0; mt < 2; ++mt)
#pragma unroll
            for (int h = 0; h < 2; ++h)
                af[mt][h] = *reinterpret_cast<const half8*>(
                    Ab + (t.wm + mt * 32 + t.l31) * 32 + (((h * 2 + t.half) ^ fsw) * 8));
#pragma unroll
        for (int nt = 0; nt < 2; ++nt)
#pragma unroll
            for (int h = 0; h < 2; ++h)
                bf[nt][h] = *reinterpret_cast<const half8*>(
                    Bb + (t.wn + nt * 32 + t.l31) * 32 + (((h * 2 + t.half) ^ fsw) * 8));
#pragma unroll
        for (int h = 0; h < 2; ++h)
#pragma unroll
            for (int mt = 0; mt < 2; ++mt)
#pragma unroll
                for (int nt = 0; nt < 2; ++nt)
                    acc[mt][nt] = __builtin_amdgcn_mfma_f32_32x32x16_f16(af[mt][h], bf[nt][h], acc[mt][nt], 0, 0, 0);
        WAIT_LGKM0();
        sc = (sc == 2) ? 0 : sc + 1;
        sp = (sp == 2) ? 0 : sp + 1;
    }
}

// ---------------------------------------------------------------- GEMM1: silu(H@Wi) -> u, vT, q, k  (32x32 MFMA)
// 1D grid 1600, XCD-banded: xcd=f%8 owns m-band [8*xcd,8*xcd+8); n slow within band.
__global__ __launch_bounds__(256) void gemm1_kernel(
    const _Float16* __restrict__ Hb, const _Float16* __restrict__ WiT,
    const float* __restrict__ qg, const float* __restrict__ kg,
    _Float16* __restrict__ u, _Float16* __restrict__ vT,
    _Float16* __restrict__ q, _Float16* __restrict__ k)
{
    __shared__ _Float16 smem[24576];
    TileCtx t = make_ctx();
    const int f = blockIdx.x;
    const int xcd = f & 7, i = f >> 3;
    const int m0 = ((xcd << 3) | (i & 7)) * 128;
    const int n0 = (i >> 3) * 128;

    floatx16 acc[2][2] = {};
    gemm_mainloop_3s32(t, Hb + (size_t)m0 * HID, HID, WiT + (size_t)n0 * HID, HID, HID, smem, acc);

    // C/D 32x32: col = lane&31, row = (reg&3) + 8*(reg>>2) + 4*(lane>>5)
    if (n0 >= INTER && n0 < 2 * INTER) {
        __syncthreads();   // mainloop has no trailing barrier; smem reused below
        const int bb = m0 >> 11, sloc = m0 & (SEQ - 1), cI = n0 - INTER;
#pragma unroll
        for (int mt = 0; mt < 2; ++mt) {
#pragma unroll
            for (int nt = 0; nt < 2; ++nt) {
                int c = t.wn + nt * 32 + t.l31;
#pragma unroll
                for (int reg = 0; reg < 16; ++reg) {
                    int r = t.wm + mt * 32 + (reg & 3) + 8 * (reg >> 2) + 4 * t.half;
                    float x = acc[mt][nt][reg];
                    float y = x / (1.0f + __expf(-x));   // silu
                    smem[c * 128 + (r ^ ((c & 15) << 3))] = (_Float16)y;
                }
            }
        }
        __syncthreads();
#pragma unroll
        for (int p = 0; p < 8; ++p) {
            int chunk = t.tid + p * 256;       // 2048 chunks of 8 halves
            int cl = chunk >> 4, sc = chunk & 15;
            int scs = sc ^ (cl & 15);
            half8 v = *reinterpret_cast<const half8*>(smem + cl * 128 + scs * 8);
            *reinterpret_cast<half8*>(vT + ((size_t)bb * INTER + cI + cl) * SEQ + sloc + sc * 8) = v;
        }
    } else {
#pragma unroll
        for (int mt = 0; mt < 2; ++mt) {
#pragma unroll
            for (int nt = 0; nt < 2; ++nt) {
                int col = n0 + t.wn + nt * 32 + t.l31;
#pragma unroll
                for (int reg = 0; reg < 16; ++reg) {
                    int row = m0 + t.wm + mt * 32 + (reg & 3) + 8 * (reg >> 2) + 4 * t.half;
                    float x = acc[mt][nt][reg];
                    float y = x / (1.0f + __expf(-x));   // silu
                    if (n0 < INTER) {
                        u[(size_t)row * INTER + col] = (_Float16)y;
                    } else {
                        int c = col - 2 * INTER;
                        q[(size_t)row * DK + c] = (_Float16)(y * qg[c]);
                        k[(size_t)row * DK + c] = (_Float16)(y * kg[c]);
                    }
                }
            }
        }
    }
}

// ---------------------------------------------------------------- scores + softmax -> P (f16)
// 1D grid 512, XCD-batched: xcd=f&7 handles batch xcd>>1 only (k_b L2-resident).
__global__ __launch_bounds__(256) void scores_kernel(
    const _Float16* __restrict__ q, const _Float16* __restrict__ k,
    const int* __restrict__ mask, const float* __restrict__ scales,
    _Float16* __restrict__ P)
{
    const int f = blockIdx.x;
    const int xcd = f & 7, i = f >> 3;          // i: 0..63
    const int b = xcd >> 1;
    const int m0 = ((xcd & 1) * 64 + i) * 16;
    const int tid = threadIdx.x;
    const int wave = tid >> 6, lane = tid & 63, quad = lane >> 4, l16 = lane & 15;
    const float scale = scales[b];

    half8 aq[4];
    const _Float16* qrow = q + (b * SEQ + m0 + l16) * DK + quad * 8;
#pragma unroll
    for (int kk = 0; kk < 4; ++kk) aq[kk] = *reinterpret_cast<const half8*>(qrow + kk * 32);

    floatx4 sc[32];
#pragma unroll
    for (int nt = 0; nt < 32; ++nt) {
        int n0 = nt * 64 + wave * 16;
        const _Float16* krow = k + (b * SEQ + n0 + l16) * DK + quad * 8;
        floatx4 acc = {};
#pragma unroll
        for (int kk = 0; kk < 4; ++kk) {
            half8 bq = *reinterpret_cast<const half8*>(krow + kk * 32);
            acc = __builtin_amdgcn_mfma_f32_16x16x32_f16(aq[kk], bq, acc, 0, 0, 0);
        }
        sc[nt] = acc;
    }

    const float rs = 0.08838834764831845f * scale;
    const float mval = -1e12f * scale;
    float rmax[4] = {-3.4e38f, -3.4e38f, -3.4e38f, -3.4e38f};
#pragma unroll
    for (int nt = 0; nt < 32; ++nt) {
        int ncol = nt * 64 + wave * 16 + l16;
        bool mok = mask[b * SEQ + ncol] != 0;
#pragma unroll
        for (int i2 = 0; i2 < 4; ++i2) {
            float s = mok ? sc[nt][i2] * rs : mval;
            sc[nt][i2] = s;
            rmax[i2] = fmaxf(rmax[i2], s);
        }
    }
#pragma unroll
    for (int i2 = 0; i2 < 4; ++i2) {
#pragma unroll
        for (int off = 1; off < 16; off <<= 1)
            rmax[i2] = fmaxf(rmax[i2], __shfl_xor(rmax[i2], off, 64));
    }
    __shared__ float redmax[4][16];
    __shared__ float redsum[4][16];
    if (l16 == 0) {
#pragma unroll
        for (int i2 = 0; i2 < 4; ++i2) redmax[wave][quad * 4 + i2] = rmax[i2];
    }
    __syncthreads();
#pragma unroll
    for (int i2 = 0; i2 < 4; ++i2) {
        int r = quad * 4 + i2;
        rmax[i2] = fmaxf(fmaxf(redmax[0][r], redmax[1][r]), fmaxf(redmax[2][r], redmax[3][r]));
    }
    float rsum[4] = {0.f, 0.f, 0.f, 0.f};
#pragma unroll
    for (int nt = 0; nt < 32; ++nt) {
#pragma unroll
        for (int i2 = 0; i2 < 4; ++i2) {
            float e = __expf(sc[nt][i2] - rmax[i2]);
            sc[nt][i2] = e;
            rsum[i2] += e;
        }
    }
#pragma unroll
    for (int i2 = 0; i2 < 4; ++i2) {
#pragma unroll
        for (int off = 1; off < 16; off <<= 1) rsum[i2] += __shfl_xor(rsum[i2], off, 64);
    }
    if (l16 == 0) {
#pragma unroll
        for (int i2 = 0; i2 < 4; ++i2) redsum[wave][quad * 4 + i2] = rsum[i2];
    }
    __syncthreads();
#pragma unroll
    for (int i2 = 0; i2 < 4; ++i2) {
        int r = quad * 4 + i2;
        float tot = redsum[0][r] + redsum[1][r] + redsum[2][r] + redsum[3][r];
        float inv = 1.0f / tot;
        int row = m0 + r;
        _Float16* Prow = P + ((size_t)b * SEQ + row) * SEQ;
#pragma unroll
        for (int nt = 0; nt < 32; ++nt) {
            int ncol = nt * 64 + wave * 16 + l16;
            Prow[ncol] = (_Float16)(sc[nt][i2] * inv);
        }
    }
}

// ---------------------------------------------------------------- PV: u <- u .* (P @ v)  (32x32 MFMA)
// 1D grid 768: xcd=f%8, i=f/8 (0..95); batch=i/24; j=i%24; m=xcd*2+(j&1); n=j/2.
__global__ __launch_bounds__(256) void pv_kernel(
    const _Float16* __restrict__ P, const _Float16* __restrict__ vT,
    _Float16* __restrict__ u)
{
    __shared__ _Float16 smem[24576];
    TileCtx t = make_ctx();
    const int f = blockIdx.x;
    const int xcd = f & 7, i = f >> 3;
    const int b = i / 24, j = i % 24;
    const int m0 = (xcd * 2 + (j & 1)) * 128;
    const int n0 = (j >> 1) * 128;
    const _Float16* Pb  = P  + (size_t)b * SEQ * SEQ;
    const _Float16* vTb = vT + (size_t)b * INTER * SEQ;

    floatx16 acc[2][2] = {};
    gemm_mainloop_3s32(t, Pb + (size_t)m0 * SEQ, SEQ, vTb + (size_t)n0 * SEQ, SEQ, SEQ, smem, acc);

#pragma unroll
    for (int mt = 0; mt < 2; ++mt) {
#pragma unroll
        for (int nt = 0; nt < 2; ++nt) {
            int col = n0 + t.wn + nt * 32 + t.l31;
#pragma unroll
            for (int reg = 0; reg < 16; ++reg) {
                int row = m0 + t.wm + mt * 32 + (reg & 3) + 8 * (reg >> 2) + 4 * t.half;
                size_t gidx = ((size_t)(b * SEQ + row)) * INTER + col;
                float uv = (float)u[gidx];
                u[gidx] = (_Float16)(acc[mt][nt][reg] * uv);
            }
        }
    }
}

// ---------------------------------------------------------------- GEMM2: out = t @ Wo (fp32 out, 32x32 MFMA)
// 1D grid 384: xcd=f%8, i=f/8 (0..47); m=xcd*8+(i&7); n=i>>3 (0..5).
__global__ __launch_bounds__(256) void gemm2_kernel(
    const _Float16* __restrict__ tin, const _Float16* __restrict__ WoT,
    float* __restrict__ out)
{
    __shared__ _Float16 smem[24576];
    TileCtx t = make_ctx();
    const int f = blockIdx.x;
    const int xcd = f & 7, i = f >> 3;
    const int m0 = ((xcd << 3) | (i & 7)) * 128;
    const int n0 = (i >> 3) * 128;

    floatx16 acc[2][2] = {};
    gemm_mainloop_3s32(t, tin + (size_t)m0 * INTER, INTER, WoT + (size_t)n0 * INTER, INTER, INTER, smem, acc);

#pragma unroll
    for (int mt = 0; mt < 2; ++mt) {
#pragma unroll
        for (int nt = 0; nt < 2; ++nt) {
            int col = n0 + t.wn + nt * 32 + t.l31;
#pragma unroll
            for (int reg = 0; reg < 16; ++reg) {
                int row = m0 + t.wm + mt * 32 + (reg & 3) + 8 * (reg >> 2) + 4 * t.half;
                out[(size_t)row * HID + col] = acc[mt][nt][reg];
            }
        }
    }
}

// ---------------------------------------------------------------- launch
extern "C" void kernel_launch(void* const* d_in, const int* in_sizes, int n_in,
                              void* d_out, int out_size, void* d_ws, size_t ws_size,
                              hipStream_t stream) {
    const float* H    = (const float*)d_in[0];
    const float* Wi   = (const float*)d_in[1];
    const float* Wo   = (const float*)d_in[2];
    const float* qg   = (const float*)d_in[3];
    const float* kg   = (const float*)d_in[4];
    const int*   mask = (const int*)d_in[5];
    float* out = (float*)d_out;

    char* base = (char*)d_ws;
    size_t off = 0;
    auto alloc = [&](size_t bytes) { void* p = base + off; off = (off + bytes + 255) & ~(size_t)255; return p; };
    _Float16* Hb   = (_Float16*)alloc((size_t)MROWS * HID * 2);
    _Float16* WiT  = (_Float16*)alloc((size_t)NTOT * HID * 2);
    _Float16* WoT  = (_Float16*)alloc((size_t)HID * INTER * 2);
    _Float16* u    = (_Float16*)alloc((size_t)MROWS * INTER * 2);   // becomes t in-place after pv
    _Float16* vT   = (_Float16*)alloc((size_t)BATCH * INTER * SEQ * 2);
    _Float16* q    = (_Float16*)alloc((size_t)MROWS * DK * 2);
    _Float16* k    = (_Float16*)alloc((size_t)MROWS * DK * 2);
    _Float16* P    = (_Float16*)alloc((size_t)BATCH * SEQ * SEQ * 2);
    float*    scales = (float*)alloc(4 * sizeof(float));

    {
        int n = MROWS * HID;
        cast_h_kernel<<<n / 8 / 256, 256, 0, stream>>>(H, Hb, n);
        trans_wi_kernel<<<dim3(NTOT / 32, HID / 32), dim3(32, 8), 0, stream>>>(Wi, WiT);
        trans_wo_kernel<<<dim3(HID / 32, INTER / 32), dim3(32, 8), 0, stream>>>(Wo, WoT);
        mask_scales_kernel<<<BATCH, 256, 0, stream>>>(mask, scales);
    }
    // GEMM1: M=8192 N=3200 K=768
    gemm1_kernel<<<1600, 256, 0, stream>>>(Hb, WiT, qg, kg, u, vT, q, k);
    // scores + softmax -> P
    scores_kernel<<<512, 256, 0, stream>>>(q, k, mask, scales, P);
    // PV: per batch M=2048 N=1536 K=2048
    pv_kernel<<<768, 256, 0, stream>>>(P, vT, u);
    // GEMM2: M=8192 N=768 K=1536
    gemm2_kernel<<<384, 256, 0, stream>>>(u, WoT, out);
}

// Round 16
// 308.516 us; speedup vs baseline: 1.0173x; 1.0173x over previous
//
#include <hip/hip_runtime.h>
#include <hip/hip_bf16.h>
#include <math.h>

// Problem constants
#define BATCH 4
#define SEQ   2048
#define HID   768
#define INTER 1536
#define DK    128
#define NTOT  3200      // 2*INTER + DK
#define MROWS 8192      // BATCH*SEQ
#define LN512 6.2383246250395075f

typedef _Float16 half8   __attribute__((ext_vector_type(8)));
typedef float    floatx4 __attribute__((ext_vector_type(4)));
typedef float    floatx16 __attribute__((ext_vector_type(16)));

typedef const __attribute__((address_space(1))) unsigned int* gas1_t;
typedef __attribute__((address_space(3))) unsigned int* las3_t;

static __device__ __forceinline__ void load16(const _Float16* g, _Float16* l) {
    __builtin_amdgcn_global_load_lds((gas1_t)g, (las3_t)l, 16, 0, 0);
}
#define WAIT_VM(N)    asm volatile("s_waitcnt vmcnt(" #N ")" ::: "memory")
#define WAIT_LGKM0()  asm volatile("s_waitcnt lgkmcnt(0)" ::: "memory")
#define BARRIER_RAW() asm volatile("s_barrier" ::: "memory")

// ---------------------------------------------------------------- prep kernels
__global__ void cast_h_kernel(const float* __restrict__ in, _Float16* __restrict__ out, int n) {
    int i = (blockIdx.x * blockDim.x + threadIdx.x) * 8;
    if (i < n) {
        float4 a = *reinterpret_cast<const float4*>(in + i);
        float4 b = *reinterpret_cast<const float4*>(in + i + 4);
        half8 h = {(_Float16)a.x, (_Float16)a.y, (_Float16)a.z, (_Float16)a.w,
                   (_Float16)b.x, (_Float16)b.y, (_Float16)b.z, (_Float16)b.w};
        *reinterpret_cast<half8*>(out + i) = h;
    }
}

__global__ void trans_wi_kernel(const float* __restrict__ Wi, _Float16* __restrict__ WiT) {
    __shared__ _Float16 tile[32][33];
    const int c0 = blockIdx.x * 32, r0 = blockIdx.y * 32;
    const int tx = threadIdx.x, ty = threadIdx.y;
#pragma unroll
    for (int j = 0; j < 32; j += 8)
        tile[tx][ty + j] = (_Float16)Wi[(size_t)(r0 + ty + j) * NTOT + c0 + tx];
    __syncthreads();
#pragma unroll
    for (int j = 0; j < 32; j += 8)
        WiT[(size_t)(c0 + ty + j) * HID + r0 + tx] = tile[ty + j][tx];
}

__global__ void trans_wo_kernel(const float* __restrict__ Wo, _Float16* __restrict__ WoT) {
    __shared__ _Float16 tile[32][33];
    const int c0 = blockIdx.x * 32, r0 = blockIdx.y * 32;
    const int tx = threadIdx.x, ty = threadIdx.y;
#pragma unroll
    for (int j = 0; j < 32; j += 8)
        tile[tx][ty + j] = (_Float16)Wo[(size_t)(r0 + ty + j) * HID + c0 + tx];
    __syncthreads();
#pragma unroll
    for (int j = 0; j < 32; j += 8)
        WoT[(size_t)(c0 + ty + j) * INTER + r0 + tx] = tile[ty + j][tx];
}

__global__ void mask_scales_kernel(const int* __restrict__ mask, float* __restrict__ scales) {
    __shared__ int sh[256];
    int b = blockIdx.x;
    int s = 0;
    for (int i = threadIdx.x; i < SEQ; i += 256) s += mask[b * SEQ + i];
    sh[threadIdx.x] = s;
    __syncthreads();
    for (int off = 128; off > 0; off >>= 1) {
        if (threadIdx.x < off) sh[threadIdx.x] += sh[threadIdx.x + off];
        __syncthreads();
    }
    if (threadIdx.x == 0) scales[b] = logf((float)sh[0]) / LN512;
}

// ---------------------------------------------------------------- shared tile ctx
struct TileCtx {
    int tid, wave, lane, quad, l16, l31, half, wm, wn, c0, c1;
};
static __device__ __forceinline__ TileCtx make_ctx() {
    TileCtx t;
    t.tid = threadIdx.x;
    t.wave = t.tid >> 6; t.lane = t.tid & 63;
    t.quad = t.lane >> 4; t.l16 = t.lane & 15;
    t.l31 = t.lane & 31;  t.half = t.lane >> 5;
    t.wm = (t.wave & 1) * 64;
    t.wn = (t.wave >> 1) * 64;
    t.c0 = t.tid;
    t.c1 = t.tid + 256;
    return t;
}

// ================================================================ mainloop: 32x32x16, 3-slot/48KB, 1 barrier/iter
// R16 bisect: chunk swizzle reverted to the s16 family s(r) = (r>>1)&3 — the
// pattern that measured conflict-free (0.39M) in the R11-R13 16x16 loops.
// (R15's ((r>>1)^(r>>3))&3 measured 6.09M conflicts; both are per-row chunk
// bijections so correctness is identical — this isolates the swizzle pattern.)
static __device__ __forceinline__ void gemm_mainloop_3s32(
    const TileCtx& t,
    const _Float16* __restrict__ Ag, int lda,
    const _Float16* __restrict__ Bg, int ldb,
    int K, _Float16* smem, floatx16 acc[2][2])
{
    const int r0i = t.c0 >> 2, s0 = (r0i >> 1) & 3;
    const int r1i = t.c1 >> 2, s1 = (r1i >> 1) & 3;
    const int ak0 = ((t.c0 & 3) ^ s0) * 8;
    const int ak1 = ((t.c1 & 3) ^ s1) * 8;
    const _Float16* a0 = Ag + (size_t)r0i * lda + ak0;
    const _Float16* a1 = Ag + (size_t)r1i * lda + ak1;
    const _Float16* b0 = Bg + (size_t)r0i * ldb + ak0;
    const _Float16* b1 = Bg + (size_t)r1i * ldb + ak1;
    _Float16* Asl = smem + t.c0 * 8;
    _Float16* Bsl = smem + 12288 + t.c0 * 8;
    const int nIter = K >> 5;

    const int fsw = (t.l31 >> 1) & 3;   // matches s(row) for row = base32 + l31

    load16(a0, Asl);        load16(a1, Asl + 2048);
    load16(b0, Bsl);        load16(b1, Bsl + 2048);
    if (nIter > 1) {
        load16(a0 + 32, Asl + 4096); load16(a1 + 32, Asl + 6144);
        load16(b0 + 32, Bsl + 4096); load16(b1 + 32, Bsl + 6144);
    }

    int sc = 0, sp = 2;
    for (int k = 0; k < nIter; ++k) {
        if (k + 1 < nIter) { WAIT_VM(4); } else { WAIT_VM(0); }
        BARRIER_RAW();
        if (k + 2 < nIter) {
            const int off = sp * 4096;
            const int k0 = (k + 2) << 5;
            load16(a0 + k0, Asl + off); load16(a1 + k0, Asl + off + 2048);
            load16(b0 + k0, Bsl + off); load16(b1 + k0, Bsl + off + 2048);
        }
        const _Float16* Ab = smem + sc * 4096;
        const _Float16* Bb = smem + 12288 + sc * 4096;
        half8 af[2][2], bf[2][2];   // [tile][kstep]
#pragma unroll
        for (int mt = 0; mt < 2; ++mt)
#pragma unroll
            for (int h = 0; h < 2; ++h)
                af[mt][h] = *reinterpret_cast<const half8*>(
                    Ab + (t.wm + mt * 32 + t.l31) * 32 + (((h * 2 + t.half) ^ fsw) * 8));
#pragma unroll
        for (int nt = 0; nt < 2; ++nt)
#pragma unroll
            for (int h = 0; h < 2; ++h)
                bf[nt][h] = *reinterpret_cast<const half8*>(
                    Bb + (t.wn + nt * 32 + t.l31) * 32 + (((h * 2 + t.half) ^ fsw) * 8));
#pragma unroll
        for (int h = 0; h < 2; ++h)
#pragma unroll
            for (int mt = 0; mt < 2; ++mt)
#pragma unroll
                for (int nt = 0; nt < 2; ++nt)
                    acc[mt][nt] = __builtin_amdgcn_mfma_f32_32x32x16_f16(af[mt][h], bf[nt][h], acc[mt][nt], 0, 0, 0);
        WAIT_LGKM0();
        sc = (sc == 2) ? 0 : sc + 1;
        sp = (sp == 2) ? 0 : sp + 1;
    }
}

// ---------------------------------------------------------------- GEMM1: silu(H@Wi) -> u, vT, q, k  (32x32 MFMA)
// 1D grid 1600, XCD-banded: xcd=f%8 owns m-band [8*xcd,8*xcd+8); n slow within band.
__global__ __launch_bounds__(256) void gemm1_kernel(
    const _Float16* __restrict__ Hb, const _Float16* __restrict__ WiT,
    const float* __restrict__ qg, const float* __restrict__ kg,
    _Float16* __restrict__ u, _Float16* __restrict__ vT,
    _Float16* __restrict__ q, _Float16* __restrict__ k)
{
    __shared__ _Float16 smem[24576];
    TileCtx t = make_ctx();
    const int f = blockIdx.x;
    const int xcd = f & 7, i = f >> 3;
    const int m0 = ((xcd << 3) | (i & 7)) * 128;
    const int n0 = (i >> 3) * 128;

    floatx16 acc[2][2] = {};
    gemm_mainloop_3s32(t, Hb + (size_t)m0 * HID, HID, WiT + (size_t)n0 * HID, HID, HID, smem, acc);

    // C/D 32x32: col = lane&31, row = (reg&3) + 8*(reg>>2) + 4*(lane>>5)
    if (n0 >= INTER && n0 < 2 * INTER) {
        __syncthreads();   // mainloop has no trailing barrier; smem reused below
        const int bb = m0 >> 11, sloc = m0 & (SEQ - 1), cI = n0 - INTER;
#pragma unroll
        for (int mt = 0; mt < 2; ++mt) {
#pragma unroll
            for (int nt = 0; nt < 2; ++nt) {
                int c = t.wn + nt * 32 + t.l31;
#pragma unroll
                for (int reg = 0; reg < 16; ++reg) {
                    int r = t.wm + mt * 32 + (reg & 3) + 8 * (reg >> 2) + 4 * t.half;
                    float x = acc[mt][nt][reg];
                    float y = x / (1.0f + __expf(-x));   // silu
                    smem[c * 128 + (r ^ ((c & 15) << 3))] = (_Float16)y;
                }
            }
        }
        __syncthreads();
#pragma unroll
        for (int p = 0; p < 8; ++p) {
            int chunk = t.tid + p * 256;       // 2048 chunks of 8 halves
            int cl = chunk >> 4, sc = chunk & 15;
            int scs = sc ^ (cl & 15);
            half8 v = *reinterpret_cast<const half8*>(smem + cl * 128 + scs * 8);
            *reinterpret_cast<half8*>(vT + ((size_t)bb * INTER + cI + cl) * SEQ + sloc + sc * 8) = v;
        }
    } else {
#pragma unroll
        for (int mt = 0; mt < 2; ++mt) {
#pragma unroll
            for (int nt = 0; nt < 2; ++nt) {
                int col = n0 + t.wn + nt * 32 + t.l31;
#pragma unroll
                for (int reg = 0; reg < 16; ++reg) {
                    int row = m0 + t.wm + mt * 32 + (reg & 3) + 8 * (reg >> 2) + 4 * t.half;
                    float x = acc[mt][nt][reg];
                    float y = x / (1.0f + __expf(-x));   // silu
                    if (n0 < INTER) {
                        u[(size_t)row * INTER + col] = (_Float16)y;
                    } else {
                        int c = col - 2 * INTER;
                        q[(size_t)row * DK + c] = (_Float16)(y * qg[c]);
                        k[(size_t)row * DK + c] = (_Float16)(y * kg[c]);
                    }
                }
            }
        }
    }
}

// ---------------------------------------------------------------- scores + softmax -> P (f16)
// 1D grid 512, XCD-batched: xcd=f&7 handles batch xcd>>1 only (k_b L2-resident).
__global__ __launch_bounds__(256) void scores_kernel(
    const _Float16* __restrict__ q, const _Float16* __restrict__ k,
    const int* __restrict__ mask, const float* __restrict__ scales,
    _Float16* __restrict__ P)
{
    const int f = blockIdx.x;
    const int xcd = f & 7, i = f >> 3;          // i: 0..63
    const int b = xcd >> 1;
    const int m0 = ((xcd & 1) * 64 + i) * 16;
    const int tid = threadIdx.x;
    const int wave = tid >> 6, lane = tid & 63, quad = lane >> 4, l16 = lane & 15;
    const float scale = scales[b];

    half8 aq[4];
    const _Float16* qrow = q + (b * SEQ + m0 + l16) * DK + quad * 8;
#pragma unroll
    for (int kk = 0; kk < 4; ++kk) aq[kk] = *reinterpret_cast<const half8*>(qrow + kk * 32);

    floatx4 sc[32];
#pragma unroll
    for (int nt = 0; nt < 32; ++nt) {
        int n0 = nt * 64 + wave * 16;
        const _Float16* krow = k + (b * SEQ + n0 + l16) * DK + quad * 8;
        floatx4 acc = {};
#pragma unroll
        for (int kk = 0; kk < 4; ++kk) {
            half8 bq = *reinterpret_cast<const half8*>(krow + kk * 32);
            acc = __builtin_amdgcn_mfma_f32_16x16x32_f16(aq[kk], bq, acc, 0, 0, 0);
        }
        sc[nt] = acc;
    }

    const float rs = 0.08838834764831845f * scale;
    const float mval = -1e12f * scale;
    float rmax[4] = {-3.4e38f, -3.4e38f, -3.4e38f, -3.4e38f};
#pragma unroll
    for (int nt = 0; nt < 32; ++nt) {
        int ncol = nt * 64 + wave * 16 + l16;
        bool mok = mask[b * SEQ + ncol] != 0;
#pragma unroll
        for (int i2 = 0; i2 < 4; ++i2) {
            float s = mok ? sc[nt][i2] * rs : mval;
            sc[nt][i2] = s;
            rmax[i2] = fmaxf(rmax[i2], s);
        }
    }
#pragma unroll
    for (int i2 = 0; i2 < 4; ++i2) {
#pragma unroll
        for (int off = 1; off < 16; off <<= 1)
            rmax[i2] = fmaxf(rmax[i2], __shfl_xor(rmax[i2], off, 64));
    }
    __shared__ float redmax[4][16];
    __shared__ float redsum[4][16];
    if (l16 == 0) {
#pragma unroll
        for (int i2 = 0; i2 < 4; ++i2) redmax[wave][quad * 4 + i2] = rmax[i2];
    }
    __syncthreads();
#pragma unroll
    for (int i2 = 0; i2 < 4; ++i2) {
        int r = quad * 4 + i2;
        rmax[i2] = fmaxf(fmaxf(redmax[0][r], redmax[1][r]), fmaxf(redmax[2][r], redmax[3][r]));
    }
    float rsum[4] = {0.f, 0.f, 0.f, 0.f};
#pragma unroll
    for (int nt = 0; nt < 32; ++nt) {
#pragma unroll
        for (int i2 = 0; i2 < 4; ++i2) {
            float e = __expf(sc[nt][i2] - rmax[i2]);
            sc[nt][i2] = e;
            rsum[i2] += e;
        }
    }
#pragma unroll
    for (int i2 = 0; i2 < 4; ++i2) {
#pragma unroll
        for (int off = 1; off < 16; off <<= 1) rsum[i2] += __shfl_xor(rsum[i2], off, 64);
    }
    if (l16 == 0) {
#pragma unroll
        for (int i2 = 0; i2 < 4; ++i2) redsum[wave][quad * 4 + i2] = rsum[i2];
    }
    __syncthreads();
#pragma unroll
    for (int i2 = 0; i2 < 4; ++i2) {
        int r = quad * 4 + i2;
        float tot = redsum[0][r] + redsum[1][r] + redsum[2][r] + redsum[3][r];
        float inv = 1.0f / tot;
        int row = m0 + r;
        _Float16* Prow = P + ((size_t)b * SEQ + row) * SEQ;
#pragma unroll
        for (int nt = 0; nt < 32; ++nt) {
            int ncol = nt * 64 + wave * 16 + l16;
            Prow[ncol] = (_Float16)(sc[nt][i2] * inv);
        }
    }
}

// ---------------------------------------------------------------- PV: u <- u .* (P @ v)  (32x32 MFMA)
// 1D grid 768: xcd=f%8, i=f/8 (0..95); batch=i/24; j=i%24; m=xcd*2+(j&1); n=j/2.
__global__ __launch_bounds__(256) void pv_kernel(
    const _Float16* __restrict__ P, const _Float16* __restrict__ vT,
    _Float16* __restrict__ u)
{
    __shared__ _Float16 smem[24576];
    TileCtx t = make_ctx();
    const int f = blockIdx.x;
    const int xcd = f & 7, i = f >> 3;
    const int b = i / 24, j = i % 24;
    const int m0 = (xcd * 2 + (j & 1)) * 128;
    const int n0 = (j >> 1) * 128;
    const _Float16* Pb  = P  + (size_t)b * SEQ * SEQ;
    const _Float16* vTb = vT + (size_t)b * INTER * SEQ;

    floatx16 acc[2][2] = {};
    gemm_mainloop_3s32(t, Pb + (size_t)m0 * SEQ, SEQ, vTb + (size_t)n0 * SEQ, SEQ, SEQ, smem, acc);

#pragma unroll
    for (int mt = 0; mt < 2; ++mt) {
#pragma unroll
        for (int nt = 0; nt < 2; ++nt) {
            int col = n0 + t.wn + nt * 32 + t.l31;
#pragma unroll
            for (int reg = 0; reg < 16; ++reg) {
                int row = m0 + t.wm + mt * 32 + (reg & 3) + 8 * (reg >> 2) + 4 * t.half;
                size_t gidx = ((size_t)(b * SEQ + row)) * INTER + col;
                float uv = (float)u[gidx];
                u[gidx] = (_Float16)(acc[mt][nt][reg] * uv);
            }
        }
    }
}

// ---------------------------------------------------------------- GEMM2: out = t @ Wo (fp32 out, 32x32 MFMA)
// 1D grid 384: xcd=f%8, i=f/8 (0..47); m=xcd*8+(i&7); n=i>>3 (0..5).
__global__ __launch_bounds__(256) void gemm2_kernel(
    const _Float16* __restrict__ tin, const _Float16* __restrict__ WoT,
    float* __restrict__ out)
{
    __shared__ _Float16 smem[24576];
    TileCtx t = make_ctx();
    const int f = blockIdx.x;
    const int xcd = f & 7, i = f >> 3;
    const int m0 = ((xcd << 3) | (i & 7)) * 128;
    const int n0 = (i >> 3) * 128;

    floatx16 acc[2][2] = {};
    gemm_mainloop_3s32(t, tin + (size_t)m0 * INTER, INTER, WoT + (size_t)n0 * INTER, INTER, INTER, smem, acc);

#pragma unroll
    for (int mt = 0; mt < 2; ++mt) {
#pragma unroll
        for (int nt = 0; nt < 2; ++nt) {
            int col = n0 + t.wn + nt * 32 + t.l31;
#pragma unroll
            for (int reg = 0; reg < 16; ++reg) {
                int row = m0 + t.wm + mt * 32 + (reg & 3) + 8 * (reg >> 2) + 4 * t.half;
                out[(size_t)row * HID + col] = acc[mt][nt][reg];
            }
        }
    }
}

// ---------------------------------------------------------------- launch
extern "C" void kernel_launch(void* const* d_in, const int* in_sizes, int n_in,
                              void* d_out, int out_size, void* d_ws, size_t ws_size,
                              hipStream_t stream) {
    const float* H    = (const float*)d_in[0];
    const float* Wi   = (const float*)d_in[1];
    const float* Wo   = (const float*)d_in[2];
    const float* qg   = (const float*)d_in[3];
    const float* kg   = (const float*)d_in[4];
    const int*   mask = (const int*)d_in[5];
    float* out = (float*)d_out;

    char* base = (char*)d_ws;
    size_t off = 0;
    auto alloc = [&](size_t bytes) { void* p = base + off; off = (off + bytes + 255) & ~(size_t)255; return p; };
    _Float16* Hb   = (_Float16*)alloc((size_t)MROWS * HID * 2);
    _Float16* WiT  = (_Float16*)alloc((size_t)NTOT * HID * 2);
    _Float16* WoT  = (_Float16*)alloc((size_t)HID * INTER * 2);
    _Float16* u    = (_Float16*)alloc((size_t)MROWS * INTER * 2);   // becomes t in-place after pv
    _Float16* vT   = (_Float16*)alloc((size_t)BATCH * INTER * SEQ * 2);
    _Float16* q    = (_Float16*)alloc((size_t)MROWS * DK * 2);
    _Float16* k    = (_Float16*)alloc((size_t)MROWS * DK * 2);
    _Float16* P    = (_Float16*)alloc((size_t)BATCH * SEQ * SEQ * 2);
    float*    scales = (float*)alloc(4 * sizeof(float));

    {
        int n = MROWS * HID;
        cast_h_kernel<<<n / 8 / 256, 256, 0, stream>>>(H, Hb, n);
        trans_wi_kernel<<<dim3(NTOT / 32, HID / 32), dim3(32, 8), 0, stream>>>(Wi, WiT);
        trans_wo_kernel<<<dim3(HID / 32, INTER / 32), dim3(32, 8), 0, stream>>>(Wo, WoT);
        mask_scales_kernel<<<BATCH, 256, 0, stream>>>(mask, scales);
    }
    // GEMM1: M=8192 N=3200 K=768
    gemm1_kernel<<<1600, 256, 0, stream>>>(Hb, WiT, qg, kg, u, vT, q, k);
    // scores + softmax -> P
    scores_kernel<<<512, 256, 0, stream>>>(q, k, mask, scales, P);
    // PV: per batch M=2048 N=1536 K=2048
    pv_kernel<<<768, 256, 0, stream>>>(P, vT, u);
    // GEMM2: M=8192 N=768 K=1536
    gemm2_kernel<<<384, 256, 0, stream>>>(u, WoT, out);
}